// Round 12
// baseline (392.582 us; speedup 1.0000x reference)
//
#include <hip/hip_runtime.h>
#include <cmath>

// Problem constants (B=4, S=4096, D=4096, E=64, K=8)
#define NTOK 16384
#define DDIM 4096
#define NEXP 64
#define TOPK 8
#define TPB   32                // tokens per block (bulk)
#define NSTEP 64                // K steps of 64
#define EPS1  3.4e-3f           // bulk f16-single margin (6 sigma of gap err)
#define EPS2  2.5e-4f           // refine32 f32 margin (huge vs 4e-7 err)

typedef __attribute__((ext_vector_type(8))) _Float16 half8;
typedef __attribute__((ext_vector_type(4))) float f32x4;

// ---------------------------------------------------------------------------
// Kernel 0: W[4096][64] fp32 -> f16 single blob in fragment-LANE order.
// blob[m 0..127][q 0..3][lane l 16B]: expert e=q*16+(l&15), k=m*32+(l>>4)*8+j.
// 128 x 4KB = 512 KB. Also zeroes the flag counters.
// ---------------------------------------------------------------------------
__global__ __launch_bounds__(256) void prep_w(const float* __restrict__ W,
                                              unsigned char* __restrict__ blob,
                                              int* __restrict__ cnts)
{
    __shared__ float tile[32][65];
    const int m = blockIdx.x;
    const int t = threadIdx.x;
    if (m == 0 && t < 4) cnts[t] = 0;
    {
        const int r = t >> 3, q8 = t & 7;
        float4 v0 = *reinterpret_cast<const float4*>(
            &W[(size_t)(m * 32 + r) * NEXP + q8 * 8]);
        float4 v1 = *reinterpret_cast<const float4*>(
            &W[(size_t)(m * 32 + r) * NEXP + q8 * 8 + 4]);
        tile[r][q8 * 8 + 0] = v0.x; tile[r][q8 * 8 + 1] = v0.y;
        tile[r][q8 * 8 + 2] = v0.z; tile[r][q8 * 8 + 3] = v0.w;
        tile[r][q8 * 8 + 4] = v1.x; tile[r][q8 * 8 + 5] = v1.y;
        tile[r][q8 * 8 + 6] = v1.z; tile[r][q8 * 8 + 7] = v1.w;
    }
    __syncthreads();
    {
        const int q = t >> 6, l = t & 63;
        const int e = q * 16 + (l & 15), kg = l >> 4;
        half8 hv;
#pragma unroll
        for (int j = 0; j < 8; ++j)
            hv[j] = (_Float16)tile[kg * 8 + j][e];
        *reinterpret_cast<half8*>(blob + (size_t)m * 4096 + q * 1024 + l * 16) = hv;
    }
}

// ---------------------------------------------------------------------------
// Kernel 1: f16-single MFMA GEMM (minimal inner-loop volume).
// 512 blocks x 512 thr (8 waves = [tg 2] x [egh 2] x [kh 2]).
// Wave = 16 tok x 32 exp x its 32k half of each 64k step; per step:
// 1 ds_read_b128 (A) + 2 direct B reg loads + 2 MFMA; half-waves also
// reg-stage the next A tile (2 global loads + 8 cvt + 1 ds_write).
// ---------------------------------------------------------------------------
__global__ __launch_bounds__(512, 4) void bulk_kernel(
    const float* __restrict__ x, const unsigned char* __restrict__ blob,
    const float* __restrict__ b,
    float* __restrict__ g_out, float* __restrict__ i_out,
    float* __restrict__ s_out,
    int* __restrict__ cnts, int* __restrict__ list1, int cap)
{
    // LDS: A dbuf 2x4KB | red [2][32][68] f32 | ls [32][65] f32
    __shared__ __align__(16) unsigned char smem[33920];

    const int tid  = threadIdx.x;
    const int l    = tid & 63;
    const int w    = tid >> 6;
    const int tg   = w & 1;
    const int egh  = (w >> 1) & 1;
    const int kh   = w >> 2;
    const int tok0 = blockIdx.x * TPB;

    // ---- stager mapping (256-thread parity group) ----
    const int sidx = tid & 255;
    const int st   = sidx >> 3;               // token 0..31
    const int sg   = sidx & 7;                // k-oct
    const float* aSrc = x + (size_t)(tok0 + st) * DDIM + sg * 8;
    const int wOff = st * 128 + ((sg * 16) ^ ((st & 7) << 4));

    // ---- compute-lane constants ----
    const int mt   = l & 15;
    const int kgrp = l >> 4;
    const int tkn  = tg * 16 + mt;
    const int rdOff = tkn * 128 + ((kh * 64 + kgrp * 16) ^ ((tkn & 7) << 4));
    const unsigned char* bBase = blob + egh * 2048 + l * 16;

    f32x4 acc0 = (f32x4){0.f,0.f,0.f,0.f};
    f32x4 acc1 = (f32x4){0.f,0.f,0.f,0.f};

    float4 ga0, ga1;
#define LOADG(s) do {                                                         \
    ga0 = *reinterpret_cast<const float4*>(aSrc + (size_t)(s) * 64);          \
    ga1 = *reinterpret_cast<const float4*>(aSrc + (size_t)(s) * 64 + 4);      \
} while (0)
#define CVTW(bufsel) do {                                                     \
    half8 hv;                                                                 \
    hv[0]=(_Float16)ga0.x; hv[1]=(_Float16)ga0.y;                             \
    hv[2]=(_Float16)ga0.z; hv[3]=(_Float16)ga0.w;                             \
    hv[4]=(_Float16)ga1.x; hv[5]=(_Float16)ga1.y;                             \
    hv[6]=(_Float16)ga1.z; hv[7]=(_Float16)ga1.w;                             \
    *reinterpret_cast<half8*>(smem + (bufsel) * 4096 + wOff) = hv;            \
} while (0)

    half8 b0c, b1c, b0n, b1n;
#define LOADB(m, r0, r1) do {                                                 \
    const unsigned char* _pb = bBase + (size_t)(m) * 4096;                    \
    r0 = *reinterpret_cast<const half8*>(_pb);                                \
    r1 = *reinterpret_cast<const half8*>(_pb + 1024);                         \
} while (0)

    // ---- prologue ----
    if (kh == 0) { LOADG(0); CVTW(0); }
    else        { LOADG(1); }
    LOADB(kh, b0c, b1c);                       // step 0: window m = kh
    asm volatile("s_waitcnt lgkmcnt(0)" ::: "memory");
    __builtin_amdgcn_s_barrier();

    for (int c = 0; c < NSTEP; ++c) {
        const int cn = (c + 1 < NSTEP) ? c + 1 : c;
        LOADB(2 * cn + kh, b0n, b1n);          // B prefetch (consumed next iter)
        if (kh == (c & 1)) {
            const int s2 = (c + 2 < NSTEP) ? c + 2 : NSTEP - 1;
            LOADG(s2);                         // A global issue (consumed next iter)
        }
        {
            half8 ah = *reinterpret_cast<const half8*>(
                smem + (c & 1) * 4096 + rdOff);
            acc0 = __builtin_amdgcn_mfma_f32_16x16x32_f16(ah, b0c, acc0, 0, 0, 0);
            acc1 = __builtin_amdgcn_mfma_f32_16x16x32_f16(ah, b1c, acc1, 0, 0, 0);
        }
        if ((kh == ((c + 1) & 1)) && (c + 1 < NSTEP)) CVTW((c + 1) & 1);
        asm volatile("s_waitcnt lgkmcnt(0)" ::: "memory");
        __builtin_amdgcn_s_barrier();
        b0c = b0n; b1c = b1n;
    }
#undef LOADG
#undef CVTW
#undef LOADB

    // ---- K-half partials -> red[2][32][68] ----
    float* redf = (float*)(smem + 8192);
    float* lsf  = (float*)(smem + 25600);     // [32][65]
#pragma unroll
    for (int r = 0; r < 4; ++r) {
        const int t_ = tg * 16 + kgrp * 4 + r;
        redf[(kh * 32 + t_) * 68 + egh * 32 + mt]      = acc0[r];
        redf[(kh * 32 + t_) * 68 + egh * 32 + 16 + mt] = acc1[r];
    }
    __syncthreads();

    // ---- fixed-order reduce + bias + sigmoid + s_out + logits ----
    {
        const int t  = tid >> 4;
        const int e0 = (tid & 15) * 4;
        float4 v0 = *reinterpret_cast<const float4*>(&redf[t * 68 + e0]);
        float4 v1 = *reinterpret_cast<const float4*>(&redf[(32 + t) * 68 + e0]);
        float4 bv = *reinterpret_cast<const float4*>(&b[e0]);
        float s0 = v0.x + v1.x + bv.x;
        float s1 = v0.y + v1.y + bv.y;
        float s2 = v0.z + v1.z + bv.z;
        float s3 = v0.w + v1.w + bv.w;
        lsf[t * 65 + e0 + 0] = s0; lsf[t * 65 + e0 + 1] = s1;
        lsf[t * 65 + e0 + 2] = s2; lsf[t * 65 + e0 + 3] = s3;
        float4 sv;
        sv.x = 1.0f / (1.0f + __expf(-s0));
        sv.y = 1.0f / (1.0f + __expf(-s1));
        sv.z = 1.0f / (1.0f + __expf(-s2));
        sv.w = 1.0f / (1.0f + __expf(-s3));
        *reinterpret_cast<float4*>(&s_out[(size_t)(tok0 + t) * NEXP + e0]) = sv;
    }
    __syncthreads();

    // ---- top-10 scan, one lane per token; flag ambiguous (EPS1) ----
    if (tid < TPB) {
        const int t = tid;
        float val[10];
        int   idx[10];
#pragma unroll
        for (int j = 0; j < 10; ++j) { val[j] = -1e30f; idx[j] = 0; }
        for (int e = 0; e < NEXP; ++e) {
            float v = lsf[t * 65 + e];
            int  ei = e;
#pragma unroll
            for (int j = 0; j < 10; ++j) {
                if (v > val[j]) {   // strict > keeps lower index first on ties
                    float tv = val[j]; val[j] = v; v = tv;
                    int   ti = idx[j]; idx[j] = ei; ei = ti;
                }
            }
        }
        bool flag = false;
#pragma unroll
        for (int j = 0; j < 9; ++j) flag |= (val[j] - val[j + 1]) < EPS1;

        float gg[TOPK], gsum = 0.0f;
#pragma unroll
        for (int j = 0; j < TOPK; ++j) {
            gg[j] = 1.0f / (1.0f + __expf(-val[j]));
            gsum += gg[j];
        }
        const float inv = 1.0f / gsum;
        const int tglob = tok0 + t;
#pragma unroll
        for (int j = 0; j < TOPK; ++j) {
            g_out[(size_t)tglob * TOPK + j] = gg[j] * inv;
            i_out[(size_t)tglob * TOPK + j] = (float)idx[j];
        }
        if (flag) {
            int p = atomicAdd(&cnts[0], 1);
            if (p < cap) list1[p] = tglob;
        }
    }
}

// ---------------------------------------------------------------------------
// Kernel 2: batched f32-chunked refine (16 tokens per batch, W tiled in LDS).
// Rewrites s/g/i for flagged tokens; re-flags gaps < EPS2 for f64 pass.
// ---------------------------------------------------------------------------
__global__ __launch_bounds__(256) void refine32(
    const float* __restrict__ x, const float* __restrict__ W,
    const float* __restrict__ b,
    float* __restrict__ g_out, float* __restrict__ i_out,
    float* __restrict__ s_out,
    const int* __restrict__ cnts, const int* __restrict__ list1,
    int* __restrict__ flag2_cnt, int* __restrict__ list2, int cap)
{
    __shared__ float wsh[128][66];            // 33.8 KB
    __shared__ float xs[16][132];             // 8.4 KB
    __shared__ float lsr[16][65];
    __shared__ int   toks[16];

    int count = cnts[0];
    if (count > cap) count = cap;
    const int nb = (count + 15) >> 4;
    const int tid = threadIdx.x;
    const int tt  = tid >> 4;
    const int e0  = (tid & 15) * 4;

    for (int batch = blockIdx.x; batch < nb; batch += gridDim.x) {
        __syncthreads();
        if (tid < 16) {
            int idx = batch * 16 + tid;
            toks[tid] = (idx < count) ? list1[idx] : -1;
        }
        __syncthreads();
        const int mytok = toks[tt];

        float a0 = 0.f, a1 = 0.f, a2 = 0.f, a3 = 0.f;
        for (int kt = 0; kt < 32; ++kt) {
            __syncthreads();
            {   // stage W tile [128][64]
                const int r = tid >> 1, h = (tid & 1) * 32;
                const float* wr = &W[(size_t)(kt * 128 + r) * NEXP + h];
#pragma unroll
                for (int p = 0; p < 8; ++p) {
                    float4 v = *reinterpret_cast<const float4*>(wr + p * 4);
                    wsh[r][h + p * 4 + 0] = v.x; wsh[r][h + p * 4 + 1] = v.y;
                    wsh[r][h + p * 4 + 2] = v.z; wsh[r][h + p * 4 + 3] = v.w;
                }
            }
            {   // stage x rows (clamped token for inactive slots)
                const int seg = tid & 15;
                const int tk = (toks[tt] < 0) ? 0 : toks[tt];
                const float* xr = &x[(size_t)tk * DDIM + kt * 128 + seg * 8];
                float4 v0 = *reinterpret_cast<const float4*>(xr);
                float4 v1 = *reinterpret_cast<const float4*>(xr + 4);
                xs[tt][seg * 8 + 0] = v0.x; xs[tt][seg * 8 + 1] = v0.y;
                xs[tt][seg * 8 + 2] = v0.z; xs[tt][seg * 8 + 3] = v0.w;
                xs[tt][seg * 8 + 4] = v1.x; xs[tt][seg * 8 + 5] = v1.y;
                xs[tt][seg * 8 + 6] = v1.z; xs[tt][seg * 8 + 7] = v1.w;
            }
            __syncthreads();
            float c0 = 0.f, c1 = 0.f, c2 = 0.f, c3 = 0.f;
#pragma unroll 8
            for (int k = 0; k < 128; ++k) {
                const float xv = xs[tt][k];
                c0 = fmaf(xv, wsh[k][e0 + 0], c0);
                c1 = fmaf(xv, wsh[k][e0 + 1], c1);
                c2 = fmaf(xv, wsh[k][e0 + 2], c2);
                c3 = fmaf(xv, wsh[k][e0 + 3], c3);
            }
            a0 += c0; a1 += c1; a2 += c2; a3 += c3;
        }
        __syncthreads();
        lsr[tt][e0 + 0] = a0 + b[e0 + 0];
        lsr[tt][e0 + 1] = a1 + b[e0 + 1];
        lsr[tt][e0 + 2] = a2 + b[e0 + 2];
        lsr[tt][e0 + 3] = a3 + b[e0 + 3];
        __syncthreads();

        if (mytok >= 0) {   // rewrite s for all batch tokens
            float4 sv;
            sv.x = 1.0f / (1.0f + __expf(-lsr[tt][e0 + 0]));
            sv.y = 1.0f / (1.0f + __expf(-lsr[tt][e0 + 1]));
            sv.z = 1.0f / (1.0f + __expf(-lsr[tt][e0 + 2]));
            sv.w = 1.0f / (1.0f + __expf(-lsr[tt][e0 + 3]));
            *reinterpret_cast<float4*>(&s_out[(size_t)mytok * NEXP + e0]) = sv;
        }
        if (tid < 16 && toks[tid] >= 0) {
            const int tok = toks[tid];
            float val[10]; int idx[10];
#pragma unroll
            for (int j = 0; j < 10; ++j) { val[j] = -1e30f; idx[j] = 0; }
            for (int e = 0; e < NEXP; ++e) {
                float v = lsr[tid][e];
                int  ei = e;
#pragma unroll
                for (int j = 0; j < 10; ++j) {
                    if (v > val[j]) {
                        float tv = val[j]; val[j] = v; v = tv;
                        int   ti = idx[j]; idx[j] = ei; ei = ti;
                    }
                }
            }
            bool flag2 = false;
#pragma unroll
            for (int j = 0; j < 9; ++j) flag2 |= (val[j] - val[j + 1]) < EPS2;

            float gg[TOPK], gsum = 0.0f;
#pragma unroll
            for (int j = 0; j < TOPK; ++j) {
                gg[j] = 1.0f / (1.0f + __expf(-val[j]));
                gsum += gg[j];
            }
            const float inv = 1.0f / gsum;
#pragma unroll
            for (int j = 0; j < TOPK; ++j) {
                g_out[(size_t)tok * TOPK + j] = gg[j] * inv;
                i_out[(size_t)tok * TOPK + j] = (float)idx[j];
            }
            if (flag2) {
                int p = atomicAdd(flag2_cnt, 1);
                if (p < cap) list2[p] = tok;
            }
        }
    }
}

// ---------------------------------------------------------------------------
// Kernel 3: f64-exact re-rank of the residual ambiguous tokens.
// ---------------------------------------------------------------------------
__global__ __launch_bounds__(256) void refine64(
    const float* __restrict__ x, const float* __restrict__ W,
    const float* __restrict__ b, float* __restrict__ g_out,
    float* __restrict__ i_out, float* __restrict__ s_out,
    const int* __restrict__ flag_cnt, const int* __restrict__ flag_list,
    int flag_cap)
{
    __shared__ float  xs2[DDIM];
    __shared__ double red[4][NEXP];
    __shared__ double sc[NEXP];

    const int tid = threadIdx.x;
    int count = *flag_cnt;
    if (count > flag_cap) count = flag_cap;

    for (int it = blockIdx.x; it < count; it += gridDim.x) {
        const int tok = flag_list[it];
        __syncthreads();
#pragma unroll
        for (int q = 0; q < 4; ++q) {
            int fi = tid + 256 * q;
            *reinterpret_cast<float4*>(&xs2[fi * 4]) =
                *reinterpret_cast<const float4*>(&x[(size_t)tok * DDIM + fi * 4]);
        }
        __syncthreads();

        const int e    = tid & 63;
        const int part = tid >> 6;
        const int dbase = part * (DDIM / 4);
        double a = 0.0;
        for (int d = 0; d < DDIM / 4; ++d) {
            a = fma((double)xs2[dbase + d],
                    (double)W[(size_t)(dbase + d) * NEXP + e], a);
        }
        red[part][e] = a;
        __syncthreads();

        if (tid < NEXP) {
            double z = ((red[0][tid] + red[1][tid]) +
                        (red[2][tid] + red[3][tid])) + (double)b[tid];
            double s = 1.0 / (1.0 + exp(-z));
            sc[tid] = s;
            s_out[(size_t)tok * NEXP + tid] = (float)s;
        }
        __syncthreads();

        if (tid == 0) {
            double val[TOPK];
            int    idx[TOPK];
#pragma unroll
            for (int j = 0; j < TOPK; ++j) { val[j] = -1e30; idx[j] = 0; }
            for (int e2 = 0; e2 < NEXP; ++e2) {
                double v = sc[e2];
                int   ei = e2;
#pragma unroll
                for (int j = 0; j < TOPK; ++j) {
                    if (v > val[j]) {
                        double tv = val[j]; val[j] = v; v = tv;
                        int    ti = idx[j]; idx[j] = ei; ei = ti;
                    }
                }
            }
            double gsum = 0.0;
#pragma unroll
            for (int j = 0; j < TOPK; ++j) gsum += val[j];
            const double inv = 1.0 / gsum;
#pragma unroll
            for (int j = 0; j < TOPK; ++j) {
                g_out[(size_t)tok * TOPK + j] = (float)(val[j] * inv);
                i_out[(size_t)tok * TOPK + j] = (float)idx[j];
            }
        }
        __syncthreads();
    }
}

// ---------------------------------------------------------------------------
extern "C" void kernel_launch(void* const* d_in, const int* in_sizes, int n_in,
                              void* d_out, int out_size, void* d_ws, size_t ws_size,
                              hipStream_t stream)
{
    (void)in_sizes; (void)n_in; (void)out_size;
    const float* x = (const float*)d_in[0];
    const float* W = (const float*)d_in[1];
    const float* b = (const float*)d_in[2];

    float* g_out = (float*)d_out;                       // [NTOK, 8]
    float* i_out = g_out + (size_t)NTOK * TOPK;         // [NTOK, 8] indices as float
    float* s_out = i_out + (size_t)NTOK * TOPK;         // [NTOK, 64]

    const size_t OFF_L1   = 1024;
    const size_t OFF_L2   = 131072;
    const size_t OFF_BLOB = 262144;
    const size_t WS_NEED  = OFF_BLOB + 128u * 4096u;    // 768 KB
    if (ws_size < WS_NEED) return;

    char* ws = (char*)d_ws;
    int* cnts  = (int*)ws;                              // [0]=flag1 [1]=flag2
    int* list1 = (int*)(ws + OFF_L1);
    int* list2 = (int*)(ws + OFF_L2);
    unsigned char* blob = (unsigned char*)(ws + OFF_BLOB);
    int cap = NTOK;

    prep_w<<<128, 256, 0, stream>>>(W, blob, cnts);
    bulk_kernel<<<NTOK / TPB, 512, 0, stream>>>(x, blob, b,
                                                g_out, i_out, s_out,
                                                cnts, list1, cap);
    refine32<<<256, 256, 0, stream>>>(x, W, b, g_out, i_out, s_out,
                                      cnts, list1, cnts + 1, list2, cap);
    refine64<<<128, 256, 0, stream>>>(x, W, b, g_out, i_out, s_out,
                                      cnts + 1, list2, cap);
}

// Round 13
// 193.381 us; speedup vs baseline: 2.0301x; 2.0301x over previous
//
#include <hip/hip_runtime.h>
#include <cmath>

// Problem constants (B=4, S=4096, D=4096, E=64, K=8)
#define NTOK 16384
#define DDIM 4096
#define NEXP 64
#define TOPK 8
#define TPB   64                // tokens per block
#define BK    128               // K per staged step
#define NSTEP 32                // 4096 / 128
#define EPS_GAP 2.5e-4f         // ambiguity margin; f16 hi/lo err sigma ~1e-6
#define INV2048 4.8828125e-4f

typedef __attribute__((ext_vector_type(8))) _Float16 half8;
typedef __attribute__((ext_vector_type(4))) float f32x4;

__device__ __forceinline__ void gload16(const void* g, void* l) {
    __builtin_amdgcn_global_load_lds(
        (const __attribute__((address_space(1))) unsigned int*)g,
        (__attribute__((address_space(3))) unsigned int*)l, 16, 0, 0);
}

// ---------------------------------------------------------------------------
// Kernel 0 (R11-verified): W[4096][64] -> f16 hi/lo blob, fragment-LANE order.
// blob[m 0..127][q 0..3][hl][lane l*16B]: e = q*16+(l&15), k = m*32+(l>>4)*8+j.
// lo scaled by 2048 (stays normal). 128 x 8KB = 1 MB. Zeroes flag counters.
// ---------------------------------------------------------------------------
__global__ __launch_bounds__(256) void prep_w(const float* __restrict__ W,
                                              unsigned char* __restrict__ blob,
                                              int* __restrict__ cnts)
{
    __shared__ float tile[32][65];
    const int m = blockIdx.x;
    const int t = threadIdx.x;
    if (m == 0 && t < 4) cnts[t] = 0;
    {
        const int r = t >> 3, q8 = t & 7;
        float4 v0 = *reinterpret_cast<const float4*>(
            &W[(size_t)(m * 32 + r) * NEXP + q8 * 8]);
        float4 v1 = *reinterpret_cast<const float4*>(
            &W[(size_t)(m * 32 + r) * NEXP + q8 * 8 + 4]);
        tile[r][q8 * 8 + 0] = v0.x; tile[r][q8 * 8 + 1] = v0.y;
        tile[r][q8 * 8 + 2] = v0.z; tile[r][q8 * 8 + 3] = v0.w;
        tile[r][q8 * 8 + 4] = v1.x; tile[r][q8 * 8 + 5] = v1.y;
        tile[r][q8 * 8 + 6] = v1.z; tile[r][q8 * 8 + 7] = v1.w;
    }
    __syncthreads();
    {
        const int q = t >> 6, l = t & 63;
        const int e = q * 16 + (l & 15), kg = l >> 4;
        half8 hv, lv;
#pragma unroll
        for (int j = 0; j < 8; ++j) {
            float f = tile[kg * 8 + j][e];
            _Float16 h = (_Float16)f;
            hv[j] = h;
            lv[j] = (_Float16)((f - (float)h) * 2048.0f);
        }
        unsigned char* base = blob + (size_t)m * 8192 + q * 2048 + l * 16;
        *reinterpret_cast<half8*>(base)        = hv;
        *reinterpret_cast<half8*>(base + 1024) = lv;
    }
}

// ---------------------------------------------------------------------------
// Kernel 1: big-step 2-phase MFMA GEMM (m97 geometry analog).
// 256 blocks x 512 thr (8 waves = 4 tokgrp x 2 exphalf); block = 64tok x 64exp,
// BK=128 -> 32 steps. LDS 128KB: A dbuf 2x32KB (f16 hi/lo, cvt at staging,
// XOR-granule swizzle both sides), B dbuf 2x32KB (linear gload_lds from blob).
// Per thread/step: 4 A-gloads + 4 B-gload16 + 16 cvt + 4 ds_write.
// No K-split: each wave owns full K for its 16tok x 32exp -> no reduce.
// ---------------------------------------------------------------------------
__global__ __launch_bounds__(512, 2) void bulk_kernel(
    const float* __restrict__ x, const unsigned char* __restrict__ blob,
    const float* __restrict__ b,
    float* __restrict__ g_out, float* __restrict__ i_out,
    float* __restrict__ s_out,
    int* __restrict__ cnts, int* __restrict__ list1, int cap)
{
    // A: buf*32768 + hl*16384 + tok*256 + granule*16   (0 .. 64K)
    // B: 65536 + buf*32768 + s*8192 + q*2048 + hl*1024 + lane*16
    __shared__ __align__(16) unsigned char smem[131072];

    const int tid  = threadIdx.x;
    const int l    = tid & 63;
    const int w    = tid >> 6;
    const int tg   = w & 3;                   // token group (16 tokens)
    const int eh   = w >> 2;                  // expert half (32 experts)
    const int tok0 = blockIdx.x * TPB;

    // ---- stager mapping: thread = (token 0..63) x (16-float k-segment 0..7)
    const int sTok = tid >> 3;
    const int kseg = tid & 7;
    const int sswz = sTok & 15;
    const float* aSrc = x + (size_t)(tok0 + sTok) * DDIM + kseg * 16;
    const unsigned char* bSrc = blob + tid * 16;

    float4 ga0, ga1, ga2, ga3;
#define LOADG(c) do {                                                         \
    const float* _p = aSrc + (size_t)(c) * BK;                                \
    ga0 = *reinterpret_cast<const float4*>(_p);                               \
    ga1 = *reinterpret_cast<const float4*>(_p + 4);                           \
    ga2 = *reinterpret_cast<const float4*>(_p + 8);                           \
    ga3 = *reinterpret_cast<const float4*>(_p + 12);                          \
} while (0)

#define CVT4(v, hv, lv, j0) do {                                              \
    _Float16 h0=(_Float16)v.x; hv[j0+0]=h0; lv[j0+0]=(_Float16)((v.x-(float)h0)*2048.0f); \
    _Float16 h1=(_Float16)v.y; hv[j0+1]=h1; lv[j0+1]=(_Float16)((v.y-(float)h1)*2048.0f); \
    _Float16 h2=(_Float16)v.z; hv[j0+2]=h2; lv[j0+2]=(_Float16)((v.z-(float)h2)*2048.0f); \
    _Float16 h3=(_Float16)v.w; hv[j0+3]=h3; lv[j0+3]=(_Float16)((v.w-(float)h3)*2048.0f); \
} while (0)

#define CVTW(bufsel) do {                                                     \
    half8 hv0, lv0, hv1, lv1;                                                 \
    CVT4(ga0, hv0, lv0, 0); CVT4(ga1, hv0, lv0, 4);                           \
    CVT4(ga2, hv1, lv1, 0); CVT4(ga3, hv1, lv1, 4);                           \
    unsigned char* _base = smem + (bufsel) * 32768 + sTok * 256;              \
    const int _g0 = kseg * 2;                                                 \
    *reinterpret_cast<half8*>(_base + (((_g0    ) ^ sswz) * 16))         = hv0; \
    *reinterpret_cast<half8*>(_base + (((_g0 + 1) ^ sswz) * 16))         = hv1; \
    *reinterpret_cast<half8*>(_base + 16384 + (((_g0    ) ^ sswz) * 16)) = lv0; \
    *reinterpret_cast<half8*>(_base + 16384 + (((_g0 + 1) ^ sswz) * 16)) = lv1; \
} while (0)

#define STAGEB(bufsel, c) do {                                                \
    const unsigned char* _s = bSrc + (size_t)(c) * 32768;                     \
    unsigned char* _d = smem + 65536 + (bufsel) * 32768 + tid * 16;           \
    gload16(_s,         _d);                                                  \
    gload16(_s +  8192, _d +  8192);                                          \
    gload16(_s + 16384, _d + 16384);                                          \
    gload16(_s + 24576, _d + 24576);                                          \
} while (0)

    // ---- compute-lane constants ----
    const int mt   = l & 15;
    const int kgrp = l >> 4;
    const int tkn  = tg * 16 + mt;            // token row in block
    const int cswz = tkn & 15;

    f32x4 accM0 = (f32x4){0.f,0.f,0.f,0.f}, accC0 = (f32x4){0.f,0.f,0.f,0.f};
    f32x4 accM1 = (f32x4){0.f,0.f,0.f,0.f}, accC1 = (f32x4){0.f,0.f,0.f,0.f};

#define COMPUTE(bufsel) do {                                                  \
    const unsigned char* _ab = smem + (bufsel) * 32768 + tkn * 256;           \
    const unsigned char* _bb = smem + 65536 + (bufsel) * 32768 +              \
                               (eh * 2) * 2048 + l * 16;                      \
    _Pragma("unroll")                                                         \
    for (int s = 0; s < 4; ++s) {                                             \
        const int _ag = ((s * 4 + kgrp) ^ cswz) * 16;                         \
        half8 ah = *reinterpret_cast<const half8*>(_ab + _ag);                \
        half8 al = *reinterpret_cast<const half8*>(_ab + 16384 + _ag);        \
        const unsigned char* _br = _bb + s * 8192;                            \
        half8 bh0 = *reinterpret_cast<const half8*>(_br);                     \
        half8 bl0 = *reinterpret_cast<const half8*>(_br + 1024);              \
        half8 bh1 = *reinterpret_cast<const half8*>(_br + 2048);              \
        half8 bl1 = *reinterpret_cast<const half8*>(_br + 3072);              \
        accM0 = __builtin_amdgcn_mfma_f32_16x16x32_f16(ah, bh0, accM0, 0, 0, 0); \
        accC0 = __builtin_amdgcn_mfma_f32_16x16x32_f16(ah, bl0, accC0, 0, 0, 0); \
        accC0 = __builtin_amdgcn_mfma_f32_16x16x32_f16(al, bh0, accC0, 0, 0, 0); \
        accM1 = __builtin_amdgcn_mfma_f32_16x16x32_f16(ah, bh1, accM1, 0, 0, 0); \
        accC1 = __builtin_amdgcn_mfma_f32_16x16x32_f16(ah, bl1, accC1, 0, 0, 0); \
        accC1 = __builtin_amdgcn_mfma_f32_16x16x32_f16(al, bh1, accC1, 0, 0, 0); \
    }                                                                         \
} while (0)

#define WAITBAR asm volatile("s_waitcnt vmcnt(0) lgkmcnt(0)\n\ts_barrier" ::: "memory")

    // ---- prologue: fill buffer 0 ----
    LOADG(0);
    STAGEB(0, 0);
    CVTW(0);            // compiler inserts the ga wait
    WAITBAR;

    for (int c = 0; c < NSTEP; ++c) {
        if (c + 1 < NSTEP) { LOADG(c + 1); STAGEB((c + 1) & 1, c + 1); }
        COMPUTE(c & 1);
        if (c + 1 < NSTEP) CVTW((c + 1) & 1);
        WAITBAR;
    }

    // ---- epilogue: logits + sigmoid + s_out (smem reused as ls[64][65]) ----
    float* ls = (float*)smem;
#pragma unroll
    for (int f = 0; f < 2; ++f) {
        const int e = eh * 32 + f * 16 + mt;
        const float be = b[e];
        const f32x4 aM = f ? accM1 : accM0;
        const f32x4 aC = f ? accC1 : accC0;
#pragma unroll
        for (int r = 0; r < 4; ++r) {
            const int trow = tg * 16 + kgrp * 4 + r;
            const float lg = (aM[r] + aC[r] * INV2048) + be;
            ls[trow * 65 + e] = lg;
            s_out[(size_t)(tok0 + trow) * NEXP + e] = 1.0f / (1.0f + __expf(-lg));
        }
    }
    __syncthreads();

    // ---- top-10 scan, one lane per token ----
    if (tid < TPB) {
        const int t = tid;
        float val[10];
        int   idx[10];
#pragma unroll
        for (int j = 0; j < 10; ++j) { val[j] = -1e30f; idx[j] = 0; }
        for (int e = 0; e < NEXP; ++e) {
            float v = ls[t * 65 + e];
            int  ei = e;
#pragma unroll
            for (int j = 0; j < 10; ++j) {
                if (v > val[j]) {   // strict > keeps lower index first on ties
                    float tv = val[j]; val[j] = v; v = tv;
                    int   ti = idx[j]; idx[j] = ei; ei = ti;
                }
            }
        }
        bool flag = false;
#pragma unroll
        for (int j = 0; j < 9; ++j) flag |= (val[j] - val[j + 1]) < EPS_GAP;

        float gg[TOPK], gsum = 0.0f;
#pragma unroll
        for (int j = 0; j < TOPK; ++j) {
            gg[j] = 1.0f / (1.0f + __expf(-val[j]));
            gsum += gg[j];
        }
        const float inv = 1.0f / gsum;
        const int tglob = tok0 + t;
#pragma unroll
        for (int j = 0; j < TOPK; ++j) {
            g_out[(size_t)tglob * TOPK + j] = gg[j] * inv;
            i_out[(size_t)tglob * TOPK + j] = (float)idx[j];
        }
        if (flag) {
            int p = atomicAdd(&cnts[0], 1);
            if (p < cap) list1[p] = tglob;
        }
    }
#undef LOADG
#undef CVT4
#undef CVTW
#undef STAGEB
#undef COMPUTE
#undef WAITBAR
}

// ---------------------------------------------------------------------------
// Kernel 2: f64-exact re-rank of ambiguous tokens (verified).
// ---------------------------------------------------------------------------
__global__ __launch_bounds__(256) void refine64(
    const float* __restrict__ x, const float* __restrict__ W,
    const float* __restrict__ b, float* __restrict__ g_out,
    float* __restrict__ i_out, float* __restrict__ s_out,
    const int* __restrict__ flag_cnt, const int* __restrict__ flag_list,
    int flag_cap)
{
    __shared__ float  xs2[DDIM];
    __shared__ double red[4][NEXP];
    __shared__ double sc[NEXP];

    const int tid = threadIdx.x;
    int count = *flag_cnt;
    if (count > flag_cap) count = flag_cap;

    for (int it = blockIdx.x; it < count; it += gridDim.x) {
        const int tok = flag_list[it];
        __syncthreads();
#pragma unroll
        for (int q = 0; q < 4; ++q) {
            int fi = tid + 256 * q;
            *reinterpret_cast<float4*>(&xs2[fi * 4]) =
                *reinterpret_cast<const float4*>(&x[(size_t)tok * DDIM + fi * 4]);
        }
        __syncthreads();

        const int e    = tid & 63;
        const int part = tid >> 6;
        const int dbase = part * (DDIM / 4);
        double a = 0.0;
        for (int d = 0; d < DDIM / 4; ++d) {
            a = fma((double)xs2[dbase + d],
                    (double)W[(size_t)(dbase + d) * NEXP + e], a);
        }
        red[part][e] = a;
        __syncthreads();

        if (tid < NEXP) {
            double z = ((red[0][tid] + red[1][tid]) +
                        (red[2][tid] + red[3][tid])) + (double)b[tid];
            double s = 1.0 / (1.0 + exp(-z));
            sc[tid] = s;
            s_out[(size_t)tok * NEXP + tid] = (float)s;
        }
        __syncthreads();

        if (tid == 0) {
            double val[TOPK];
            int    idx[TOPK];
#pragma unroll
            for (int j = 0; j < TOPK; ++j) { val[j] = -1e30; idx[j] = 0; }
            for (int e2 = 0; e2 < NEXP; ++e2) {
                double v = sc[e2];
                int   ei = e2;
#pragma unroll
                for (int j = 0; j < TOPK; ++j) {
                    if (v > val[j]) {
                        double tv = val[j]; val[j] = v; v = tv;
                        int    ti = idx[j]; idx[j] = ei; ei = ti;
                    }
                }
            }
            double gsum = 0.0;
#pragma unroll
            for (int j = 0; j < TOPK; ++j) gsum += val[j];
            const double inv = 1.0 / gsum;
#pragma unroll
            for (int j = 0; j < TOPK; ++j) {
                g_out[(size_t)tok * TOPK + j] = (float)(val[j] * inv);
                i_out[(size_t)tok * TOPK + j] = (float)idx[j];
            }
        }
        __syncthreads();
    }
}

// ---------------------------------------------------------------------------
extern "C" void kernel_launch(void* const* d_in, const int* in_sizes, int n_in,
                              void* d_out, int out_size, void* d_ws, size_t ws_size,
                              hipStream_t stream)
{
    (void)in_sizes; (void)n_in; (void)out_size;
    const float* x = (const float*)d_in[0];
    const float* W = (const float*)d_in[1];
    const float* b = (const float*)d_in[2];

    float* g_out = (float*)d_out;                       // [NTOK, 8]
    float* i_out = g_out + (size_t)NTOK * TOPK;         // [NTOK, 8] indices as float
    float* s_out = i_out + (size_t)NTOK * TOPK;         // [NTOK, 64]

    const size_t OFF_LIST = 1024;
    const size_t OFF_BLOB = 131072;
    const size_t WS_NEED  = OFF_BLOB + 128u * 8192u;    // 1.18 MB
    if (ws_size < WS_NEED) return;

    char* ws = (char*)d_ws;
    int* cnts = (int*)ws;
    int* list1 = (int*)(ws + OFF_LIST);
    unsigned char* blob = (unsigned char*)(ws + OFF_BLOB);
    int cap = NTOK;

    prep_w<<<128, 256, 0, stream>>>(W, blob, cnts);
    bulk_kernel<<<NTOK / TPB, 512, 0, stream>>>(x, blob, b,
                                                g_out, i_out, s_out,
                                                cnts, list1, cap);
    refine64<<<256, 256, 0, stream>>>(x, W, b, g_out, i_out, s_out,
                                      cnts, list1, cap);
}